// Round 5
// baseline (255.051 us; speedup 1.0000x reference)
//
#include <hip/hip_runtime.h>

// Integrate-and-fire scan over time axis, software-pipelined.
// x: [T=32, N=4194304] fp32 -> spikes same shape.
// Each thread owns one float4 column. T is processed in 4 blocks of 8.
// Loads for block b+1 are ISSUED BEFORE stores of block b, so the shared
// vmcnt FIFO never forces load consumption to wait on store completion
// (stores sit younger in the queue).
//
// Cache policy: plain loads (L3 retains ~half of the 512 MiB x across
// replays — measured FETCH 268 MB vs 537 MB); nontemporal stores (write
// stream is never re-read; don't evict x from L2/L3).

#define T_STEPS 32
#define UF 8
#define NB (T_STEPS / UF)

typedef float f32x4 __attribute__((ext_vector_type(4)));

__global__ __launch_bounds__(256) void if_scan_kernel(
    const f32x4* __restrict__ x, f32x4* __restrict__ out, int nvec) {
    int i = blockIdx.x * blockDim.x + threadIdx.x;
    if (i >= nvec) return;

    const f32x4* __restrict__ px = x + i;
    f32x4* __restrict__ po = out + i;

    float m0 = 0.f, m1 = 0.f, m2 = 0.f, m3 = 0.f;

    f32x4 buf[UF];
#pragma unroll
    for (int u = 0; u < UF; ++u)
        buf[u] = px[(size_t)u * nvec];

#pragma unroll
    for (int b = 0; b < NB; ++b) {
        f32x4 nxt[UF];
        if (b + 1 < NB) {
#pragma unroll
            for (int u = 0; u < UF; ++u)
                nxt[u] = px[(size_t)((b + 1) * UF + u) * nvec];
        }

#pragma unroll
        for (int u = 0; u < UF; ++u) {
            const int t = b * UF + u;
            f32x4 xt = buf[u];
            f32x4 s;
            m0 += xt.x; s.x = (m0 >= 1.0f) ? 1.0f : 0.0f; m0 = (s.x != 0.0f) ? 0.0f : m0;
            m1 += xt.y; s.y = (m1 >= 1.0f) ? 1.0f : 0.0f; m1 = (s.y != 0.0f) ? 0.0f : m1;
            m2 += xt.z; s.z = (m2 >= 1.0f) ? 1.0f : 0.0f; m2 = (s.z != 0.0f) ? 0.0f : m2;
            m3 += xt.w; s.w = (m3 >= 1.0f) ? 1.0f : 0.0f; m3 = (s.w != 0.0f) ? 0.0f : m3;
            __builtin_nontemporal_store(s, &po[(size_t)t * nvec]);
        }

        if (b + 1 < NB) {
#pragma unroll
            for (int u = 0; u < UF; ++u)
                buf[u] = nxt[u];
        }
    }
}

extern "C" void kernel_launch(void* const* d_in, const int* in_sizes, int n_in,
                              void* d_out, int out_size, void* d_ws, size_t ws_size,
                              hipStream_t stream) {
    const float* x = (const float*)d_in[0];
    float* out = (float*)d_out;

    const long long total = (long long)in_sizes[0];   // T*N = 134217728
    const int N = (int)(total / T_STEPS);             // 4194304 neurons
    const int nvec = N / 4;                           // 1048576 columns

    const int block = 256;
    const int grid = (nvec + block - 1) / block;      // 4096 blocks

    if_scan_kernel<<<grid, block, 0, stream>>>(
        (const f32x4*)x, (f32x4*)out, nvec);
}

// Round 6
// 242.590 us; speedup vs baseline: 1.0514x; 1.0514x over previous
//
#include <hip/hip_runtime.h>

// Integrate-and-fire scan over time axis.
// x: [T=32, N=4194304] fp32 -> spikes same shape.
// Each thread owns one float4 column, scans T with membrane in registers.
//
// Cache-policy A/B (completing the 2x2 matrix):
//   loads  NONTEMPORAL  (best measured read policy, R3: 239us)
//   stores PLAIN        (L2-allocating write-combine path — the harness
//                        fill kernel sustains 6.7 TB/s through it; NT
//                        stores measured 239-255us in R3/R4/R5)

#define T_STEPS 32

typedef float f32x4 __attribute__((ext_vector_type(4)));

__global__ __launch_bounds__(256) void if_scan_kernel(
    const f32x4* __restrict__ x, f32x4* __restrict__ out, int nvec) {
    int i = blockIdx.x * blockDim.x + threadIdx.x;
    if (i >= nvec) return;

    const f32x4* __restrict__ px = x + i;
    f32x4* __restrict__ po = out + i;

    float m0 = 0.f, m1 = 0.f, m2 = 0.f, m3 = 0.f;

#pragma unroll 8
    for (int t = 0; t < T_STEPS; ++t) {
        f32x4 xt = __builtin_nontemporal_load(&px[(size_t)t * nvec]);

        f32x4 s;
        m0 += xt.x; s.x = (m0 >= 1.0f) ? 1.0f : 0.0f; m0 = (s.x != 0.0f) ? 0.0f : m0;
        m1 += xt.y; s.y = (m1 >= 1.0f) ? 1.0f : 0.0f; m1 = (s.y != 0.0f) ? 0.0f : m1;
        m2 += xt.z; s.z = (m2 >= 1.0f) ? 1.0f : 0.0f; m2 = (s.z != 0.0f) ? 0.0f : m2;
        m3 += xt.w; s.w = (m3 >= 1.0f) ? 1.0f : 0.0f; m3 = (s.w != 0.0f) ? 0.0f : m3;

        po[(size_t)t * nvec] = s;   // plain store: L2 write-combine path
    }
}

extern "C" void kernel_launch(void* const* d_in, const int* in_sizes, int n_in,
                              void* d_out, int out_size, void* d_ws, size_t ws_size,
                              hipStream_t stream) {
    const float* x = (const float*)d_in[0];
    float* out = (float*)d_out;

    const long long total = (long long)in_sizes[0];   // T*N = 134217728
    const int N = (int)(total / T_STEPS);             // 4194304 neurons
    const int nvec = N / 4;                           // 1048576 columns

    const int block = 256;
    const int grid = (nvec + block - 1) / block;      // 4096 blocks

    if_scan_kernel<<<grid, block, 0, stream>>>(
        (const f32x4*)x, (f32x4*)out, nvec);
}

// Round 7
// 180.675 us; speedup vs baseline: 1.4117x; 1.3427x over previous
//
#include <hip/hip_runtime.h>

// Integrate-and-fire scan over time axis — fat-thread variant.
// x: [T=32, N=4194304] fp32 -> spikes same shape.
//
// Each thread owns C=4 float4 columns (16 neurons), so the whole grid is
// 1024 blocks / 262144 threads (~16 waves/CU instead of 24+/CU). Per time
// step a wave issues 4 contiguous-1KiB loads spanning a dense 4 KiB x 4
// window; each block walks a contiguous 16 KiB window per t-slice. Goal:
// fewer concurrent waves with denser per-wave bursts -> better DRAM row
// locality, less TLB/L1 churn (the 6.7 TB/s fill runs at 10% occupancy).
//
// Cache policy NT/NT — measured best (R3 239us vs plain variants 243-257):
// zero reuse inside a replay, so bypassing L2 allocation is pure win.

#define T_STEPS 32
#define C 4  // float4 columns per thread

typedef float f32x4 __attribute__((ext_vector_type(4)));

__global__ __launch_bounds__(256) void if_scan_kernel(
    const f32x4* __restrict__ x, f32x4* __restrict__ out, int nvec) {
    const int tid = threadIdx.x;
    const int blk = blockIdx.x;

    // thread's k-th column: blk*1024 + k*256 + tid  (k chunks 4KiB apart,
    // lanes contiguous within each chunk -> fully coalesced b128)
    const int base = blk * (256 * C) + tid;

    float m[C][4];
#pragma unroll
    for (int k = 0; k < C; ++k)
        m[k][0] = m[k][1] = m[k][2] = m[k][3] = 0.f;

#pragma unroll 4
    for (int t = 0; t < T_STEPS; ++t) {
        const size_t row = (size_t)t * nvec;

        f32x4 xt[C];
#pragma unroll
        for (int k = 0; k < C; ++k)
            xt[k] = __builtin_nontemporal_load(&x[row + base + k * 256]);

        f32x4 s[C];
#pragma unroll
        for (int k = 0; k < C; ++k) {
            m[k][0] += xt[k].x; s[k].x = (m[k][0] >= 1.0f) ? 1.0f : 0.0f; m[k][0] = (s[k].x != 0.0f) ? 0.0f : m[k][0];
            m[k][1] += xt[k].y; s[k].y = (m[k][1] >= 1.0f) ? 1.0f : 0.0f; m[k][1] = (s[k].y != 0.0f) ? 0.0f : m[k][1];
            m[k][2] += xt[k].z; s[k].z = (m[k][2] >= 1.0f) ? 1.0f : 0.0f; m[k][2] = (s[k].z != 0.0f) ? 0.0f : m[k][2];
            m[k][3] += xt[k].w; s[k].w = (m[k][3] >= 1.0f) ? 1.0f : 0.0f; m[k][3] = (s[k].w != 0.0f) ? 0.0f : m[k][3];
        }

#pragma unroll
        for (int k = 0; k < C; ++k)
            __builtin_nontemporal_store(s[k], &out[row + base + k * 256]);
    }
}

extern "C" void kernel_launch(void* const* d_in, const int* in_sizes, int n_in,
                              void* d_out, int out_size, void* d_ws, size_t ws_size,
                              hipStream_t stream) {
    const float* x = (const float*)d_in[0];
    float* out = (float*)d_out;

    const long long total = (long long)in_sizes[0];   // T*N = 134217728
    const int N = (int)(total / T_STEPS);             // 4194304 neurons
    const int nvec = N / 4;                           // 1048576 float4 columns

    const int block = 256;
    const int grid = nvec / (block * C);              // 1024 blocks

    if_scan_kernel<<<grid, block, 0, stream>>>(
        (const f32x4*)x, (f32x4*)out, nvec);
}